// Round 4
// baseline (151.560 us; speedup 1.0000x reference)
//
#include <hip/hip_runtime.h>
#include <cmath>

// SSIM fused kernel for B=16, C=3, H=W=512 fp32 images.
// Separable 11-tap Gaussian. Horizontal conv via float2-interleaved LDS rows
// (double-buffered, ds_read_b64); vertical via per-thread register ring of
// FOUR quantities: conv(a), conv(b), conv(a^2+b^2), conv(ab).
// One block = one (plane, 32-row stripe); 512 threads = 1 column each.
//
// Register-allocation history: launch_bounds(512,4) -> 64-VGPR cap, ring in
// AGPRs, accvgpr churn (R2: VGPR=44). launch_bounds(512,2) still chose 52
// VGPRs (R3) -- ring still partly AGPR-resident. Live-state floor is ~60+.
// This round: amdgpu_waves_per_eu(1,2) to give the allocator a 512-VGPR
// ceiling so the whole ring lands in arch VGPRs.

#define IMG_H 512
#define IMG_W 512
#define STRIPE 32
#define NSTR (IMG_H / STRIPE)      // 16
#define NPLANES 48                 // 16*3
#define NBLOCKS (NPLANES * NSTR)   // 768
#define SSIM_C1 (0.01f * 0.01f)
#define SSIM_C2 (0.03f * 0.03f)

struct W11 { float w[11]; };

__attribute__((amdgpu_flat_work_group_size(512, 512), amdgpu_waves_per_eu(1, 2)))
__global__ void ssim_main(const float* __restrict__ img1,
                          const float* __restrict__ img2,
                          float* __restrict__ blockSums, W11 wv) {
    // interleaved (a,b) pairs; cols 0..521 used (5 halo each side), pad 528
    __shared__ float2 tb[2][528];
    __shared__ float red[8];

    const int x = threadIdx.x;            // 0..511, one output column
    const int bid = blockIdx.x;
    const int plane = bid >> 4;           // /NSTR
    const int stripe = bid & (NSTR - 1);
    const int y0 = stripe * STRIPE;
    const size_t base = (size_t)plane * (IMG_H * IMG_W);

    // zero halo pads (cols 0..4 and 517..521, both buffers)
    if (x < 10) {
        const int col = (x < 5) ? x : (x + 512);
        tb[0][col] = make_float2(0.f, 0.f);
        tb[1][col] = make_float2(0.f, 0.f);
    }

    // vertical ring buffers, static-indexed via unroll
    float rA[11], rB[11], rS[11], rP[11];
    float acc = 0.f;

    // prefetch first row (r = y0-5)
    float pa = 0.f, pb = 0.f;
    {
        const int r0 = y0 - 5;
        if (r0 >= 0) {
            pa = img1[base + (size_t)r0 * IMG_W + x];
            pb = img2[base + (size_t)r0 * IMG_W + x];
        }
    }

    int buf = 0;
#pragma unroll 1
    for (int c = 0; c < 4; ++c) {
#pragma unroll
        for (int j = 0; j < 11; ++j) {
            const int i = c * 11 + j;      // 0..43; only 0..41 do work
            if (i < 42) {                  // block-uniform guard
                // stage current row into LDS as interleaved pair
                tb[buf][x + 5] = make_float2(pa, pb);
                // prefetch next row (hidden behind barrier + compute)
                pa = 0.f; pb = 0.f;
                const int rn = y0 - 4 + i;
                if (i + 1 < 42 && rn >= 0 && rn < IMG_H) {
                    pa = img1[base + (size_t)rn * IMG_W + x];
                    pb = img2[base + (size_t)rn * IMG_W + x];
                }
                __syncthreads();
                // horizontal 11-tap conv of the 4 quantities
                float h0 = 0.f, h1 = 0.f, h2 = 0.f, h3 = 0.f;
#pragma unroll
                for (int k = 0; k < 11; ++k) {
                    const float2 t = tb[buf][x + k];   // ds_read_b64
                    const float w = wv.w[k];           // SGPR
                    const float sq = fmaf(t.y, t.y, t.x * t.x); // a^2+b^2
                    const float pr = t.x * t.y;                  // a*b
                    h0 = fmaf(w, t.x, h0);
                    h1 = fmaf(w, t.y, h1);
                    h2 = fmaf(w, sq, h2);
                    h3 = fmaf(w, pr, h3);
                }
                rA[j] = h0; rB[j] = h1; rS[j] = h2; rP[j] = h3;

                if (i >= 10) {  // uniform; output row y = y0 + i - 10
                    float vA = 0.f, vB = 0.f, vS = 0.f, vP = 0.f;
#pragma unroll
                    for (int k = 0; k < 11; ++k) {
                        const int s = (j + 1 + k) % 11;  // static per (j,k)
                        const float w = wv.w[k];
                        vA = fmaf(w, rA[s], vA);
                        vB = fmaf(w, rB[s], vB);
                        vS = fmaf(w, rS[s], vS);
                        vP = fmaf(w, rP[s], vP);
                    }
                    const float mu11 = vA * vA;
                    const float mu22 = vB * vB;
                    const float mu12 = vA * vB;
                    const float num = fmaf(2.f, mu12, SSIM_C1) *
                                      fmaf(2.f, vP - mu12, SSIM_C2);
                    const float d1  = mu11 + mu22;
                    const float den = (d1 + SSIM_C1) * ((vS - d1) + SSIM_C2);
                    acc = fmaf(num, __builtin_amdgcn_rcpf(den), acc);
                }
                buf ^= 1;
            }
        }
    }

    // block reduction: wave shuffle, then 8 wave-sums via LDS
#pragma unroll
    for (int off = 32; off >= 1; off >>= 1)
        acc += __shfl_down(acc, off, 64);
    const int wave = x >> 6, lane = x & 63;
    if (lane == 0) red[wave] = acc;
    __syncthreads();
    if (x == 0) {
        float s = 0.f;
#pragma unroll
        for (int k = 0; k < 8; ++k) s += red[k];
        blockSums[bid] = s;
    }
}

__global__ void ssim_reduce(const float* __restrict__ bs,
                            float* __restrict__ out) {
    __shared__ double red[4];
    const int t = threadIdx.x;  // 256 threads
    double a = 0.0;
    for (int idx = t; idx < NBLOCKS; idx += 256) a += (double)bs[idx];
#pragma unroll
    for (int off = 32; off >= 1; off >>= 1)
        a += __shfl_down(a, off, 64);
    const int wave = t >> 6, lane = t & 63;
    if (lane == 0) red[wave] = a;
    __syncthreads();
    if (t == 0) {
        const double s = red[0] + red[1] + red[2] + red[3];
        out[0] = (float)(s / (double)((double)NPLANES * IMG_H * IMG_W));
    }
}

extern "C" void kernel_launch(void* const* d_in, const int* in_sizes, int n_in,
                              void* d_out, int out_size, void* d_ws, size_t ws_size,
                              hipStream_t stream) {
    const float* img1 = (const float*)d_in[0];
    const float* img2 = (const float*)d_in[1];
    float* out = (float*)d_out;
    float* bs = (float*)d_ws;   // 768 floats of scratch

    // Gaussian weights, faithful to reference: center 5.5, sigma 1.5
    W11 wv;
    double g[11], s = 0.0;
    for (int i = 0; i < 11; ++i) {
        const double d = (double)i - 5.5;
        g[i] = exp(-(d * d) / (2.0 * 1.5 * 1.5));
        s += g[i];
    }
    for (int i = 0; i < 11; ++i) wv.w[i] = (float)(g[i] / s);

    ssim_main<<<NBLOCKS, 512, 0, stream>>>(img1, img2, bs, wv);
    ssim_reduce<<<1, 256, 0, stream>>>(bs, out);
}